// Round 6
// baseline (183.622 us; speedup 1.0000x reference)
//
#include <hip/hip_runtime.h>

// RegLoss: l1(masked preds, targets) + 0.1 * mse(masked edge directions)
// preds, targets: [128, 1024, 151] fp32. Output: 1 fp32 scalar.
//
// Identities:
//   targets * (targets != 0) == targets       (masking targets is identity)
//   (m*pd - m*td)^2 == m*(pd - td)^2          (m in {0,1})
//   diff/(len+tiny) == (d2 > 0 ? diff*rsq(d2) : 0)  (~1e-7 rel; thresh 2.4e-2)
//
// R12: NO LDS, NO WAIT BARRIERS -- the discriminating experiment.
// Evidence to date: R6/R7/R9/R10/R11 (LDS-staged; DMA vs reg vs pinned-asm
// paths, pipeline depth 0/1/2, 16 vs 32 waves/CU) are ALL 62-64us at
// 2.5 TB/s effective, all pipes <20% busy. R11's killer datapoint:
// fully-L3-resident iterations (FETCH ~ 0 B) run the SAME 62us => not
// HBM-bound at any level; the cap is on the CU<->cache request path as
// exercised by the staged-convoy structure (4.2 B/cyc/CU = 6% of the L1
// port). No forward model from measured per-instr costs explains 62us,
// so the structure itself (burst -> vmcnt(0) -> compute convoy + LDS
// round-trip) is the last suspect standing.
//
// New shape: block owns a 64-row slab; 4 sub-slabs of 16 rows (19.3 KB,
// L1-sized). Per sub-slab:
//   A) l1 term: coalesced float4 stream of the sub-slab, accumulated
//      straight from registers (604 float4 per array, 3 loads/thread).
//   B) edge terms: gather DIRECTLY FROM GLOBAL (dwordx3 + dword loads).
//      Same lines phase A just pulled into THIS CU's L1/L2 -> cache hits;
//      L2-level traffic stays ~158MB.
// No __shared__ staging, no s_waitcnt asm, no volatile asm. Every lane has
// ~25 independent plain loads per sub-slab; the compiler pipelines them
// with its own vmcnt staircase. Reduction: shuffle + 32B of LDS.
//
// Pre-committed reading: LDS_Block_Size -> ~0, VGPR -> 64-96, WRITE ~130KB.
// Structure was the cap => main 62 -> 32-45us. Still ~62us => coalesced
// stream + L1 gather ALSO caps at 2.5 TB/s => serving-rate roofline,
// declare <<ROOFLINE>> next round.

#define N_ROWS   (128 * 1024)
#define ROW      151
#define N_EDGES  47
#define GRID     2048
#define BLOCK    256
#define ROWS_PER_BLOCK 64              // 2048 blocks * 64 rows = 131072 rows
#define SUBS     4
#define SUB_ROWS 16
#define SUB_DW   (SUB_ROWS * ROW)      // 2416 dwords per array per sub-slab
#define SUB_F4   (SUB_DW / 4)          // 604 float4 per array per sub-slab
#define SUB_TASKS (SUB_ROWS * N_EDGES) // 752 edge tasks per sub-slab

#if __has_builtin(__builtin_amdgcn_rsqf)
__device__ __forceinline__ float fast_rsq(float x) { return __builtin_amdgcn_rsqf(x); }
#else
__device__ __forceinline__ float fast_rsq(float x) {
    float r; asm volatile("v_rsq_f32 %0, %1" : "=v"(r) : "v"(x)); return r;
}
#endif

struct f3 { float x, y, z; };
__device__ __forceinline__ f3 ldg3(const float* __restrict__ p) {
    return *reinterpret_cast<const f3*>(p);     // 4B-aligned, dwordx3/x2+x1
}

// packed: low16 = parent*3 (dword offset in row), high16 = child*3
#define E(p, c) ((unsigned)((p) * 3) | ((unsigned)((c) * 3) << 16))
__constant__ unsigned c_edge[N_EDGES] = {
    E(0,1),  E(1,2),  E(2,3),  E(3,29), E(1,5),  E(5,6),  E(6,8),  E(8,9),
    E(8,13), E(8,17), E(8,21), E(8,25), E(9,10), E(10,11),E(11,12),E(13,14),
    E(14,15),E(15,16),E(17,18),E(18,19),E(19,20),E(21,22),E(22,23),E(23,24),
    E(25,26),E(26,27),E(27,28),E(29,30),E(29,34),E(29,38),E(29,42),E(29,46),
    E(30,31),E(31,32),E(32,33),E(34,35),E(35,36),E(36,37),E(38,39),E(39,40),
    E(40,41),E(42,43),E(43,44),E(44,45),E(46,47),E(47,48),E(48,49)};

// pre-summed sub-slab-relative dword addresses (fixed across sub-slabs/blocks)
struct EdgeAddr { int aP[3], aC[3], aM[3]; };

__device__ __forceinline__ void acc_l1(float4 pv, float4 tv, float& l1) {
    float a0 = (tv.x != 0.f) ? pv.x : 0.f;
    float a1 = (tv.y != 0.f) ? pv.y : 0.f;
    float a2 = (tv.z != 0.f) ? pv.z : 0.f;
    float a3 = (tv.w != 0.f) ? pv.w : 0.f;
    l1 += fabsf(a0 - tv.x) + fabsf(a1 - tv.y)
        + fabsf(a2 - tv.z) + fabsf(a3 - tv.w);
}

// one edge task, reading globals (L1/L2-hot from phase A of this sub-slab)
__device__ __forceinline__ void edge_task(
        const float* __restrict__ bp, const float* __restrict__ bt,
        int aP, int aC, int aM, float& vel) {
    f3 tp = ldg3(bt + aP);
    f3 tc = ldg3(bt + aC);
    f3 pp = ldg3(bp + aP);
    f3 pc = ldg3(bp + aC);
    float mg0 = bt[aM], mg1 = bt[aM + 47], mg2 = bt[aM + 94];
    // masked preds
    float apx = (tp.x != 0.f) ? pp.x : 0.f;
    float apy = (tp.y != 0.f) ? pp.y : 0.f;
    float apz = (tp.z != 0.f) ? pp.z : 0.f;
    float acx = (tc.x != 0.f) ? pc.x : 0.f;
    float acy = (tc.y != 0.f) ? pc.y : 0.f;
    float acz = (tc.z != 0.f) ? pc.z : 0.f;
    float pdx = apx - acx, pdy = apy - acy, pdz = apz - acz;
    float tdx = tp.x - tc.x, tdy = tp.y - tc.y, tdz = tp.z - tc.z;
    float pd2 = pdx * pdx + pdy * pdy + pdz * pdz;
    float td2 = tdx * tdx + tdy * tdy + tdz * tdz;
    float pinv = (pd2 > 0.f) ? fast_rsq(pd2) : 0.f;
    float tinv = (td2 > 0.f) ? fast_rsq(td2) : 0.f;
    float dx = pdx * pinv - tdx * tinv;
    float dy = pdy * pinv - tdy * tinv;
    float dz = pdz * pinv - tdz * tinv;
    float m0 = (mg0 != 0.f) ? 1.f : 0.f;
    float m1 = (mg1 != 0.f) ? 1.f : 0.f;
    float m2 = (mg2 != 0.f) ? 1.f : 0.f;
    vel += m0 * dx * dx + m1 * dy * dy + m2 * dz * dz;
}

__global__ __launch_bounds__(BLOCK, 4) void reg_loss_main(
        const float* __restrict__ preds, const float* __restrict__ targets,
        float* __restrict__ wsL, float* __restrict__ wsV) {
    __shared__ float redL[4], redV[4];     // 32 B -- occupancy not LDS-capped

    const int t = threadIdx.x;
    const int lane = t & 63;
    const int wave = t >> 6;

    const long long slab = (long long)blockIdx.x * (ROWS_PER_BLOCK * ROW);
    const float* sp = preds + slab;
    const float* st = targets + slab;

    // per-thread edge-task addresses (fixed across sub-slabs): 9 VGPRs
    // task = t + k*256 within a sub-slab; r = task/47, e = task%47.
    EdgeAddr ea;
#pragma unroll
    for (int k = 0; k < 3; ++k) {
        int task = t + k * 256;
        bool a = task < SUB_TASKS;
        int r = a ? task / N_EDGES : 0;
        int e = a ? task - r * N_EDGES : 0;
        int roff = r * ROW;
        unsigned pk = c_edge[e];
        ea.aP[k] = roff + (int)(pk & 0xffff);
        ea.aC[k] = roff + (int)(pk >> 16);
        ea.aM[k] = roff + e;
    }

    float l1 = 0.f, vel = 0.f;

#pragma unroll
    for (int sub = 0; sub < SUBS; ++sub) {
        const float* __restrict__ bp = sp + sub * SUB_DW;
        const float* __restrict__ bt = st + sub * SUB_DW;
        const float4* __restrict__ bp4 = reinterpret_cast<const float4*>(bp);
        const float4* __restrict__ bt4 = reinterpret_cast<const float4*>(bt);

        // ---- phase A: l1 term, coalesced float4 stream (fills L1/L2) ----
#pragma unroll
        for (int k = 0; k < 3; ++k) {
            int i = t + k * 256;
            if (k < 2 || t < (SUB_F4 - 512)) {      // k=2 active for t<92
                float4 pv = bp4[i];
                float4 tv = bt4[i];
                acc_l1(pv, tv, l1);
            }
        }

        // ---- phase B: 752 edge tasks, gather from global (cache-hot) ----
#pragma unroll
        for (int k = 0; k < 3; ++k) {
            if (k < 2 || t < (SUB_TASKS - 512)) {   // k=2 active for t<240
                edge_task(bp, bt, ea.aP[k], ea.aC[k], ea.aM[k], vel);
            }
        }
    }

    // ---- block reduction -> per-block partials ----
#pragma unroll
    for (int off = 32; off > 0; off >>= 1) {
        l1  += __shfl_down(l1, off);
        vel += __shfl_down(vel, off);
    }
    if (lane == 0) { redL[wave] = l1; redV[wave] = vel; }
    __syncthreads();
    if (t == 0) {
        wsL[blockIdx.x] = redL[0] + redL[1] + redL[2] + redL[3];
        wsV[blockIdx.x] = redV[0] + redV[1] + redV[2] + redV[3];
    }
}

__global__ __launch_bounds__(BLOCK) void reg_loss_finalize(
        const float* __restrict__ wsL, const float* __restrict__ wsV,
        float* __restrict__ out) {
    __shared__ double rl[4], rv[4];
    const int t = threadIdx.x;
    const int lane = t & 63;
    const int wave = t >> 6;
    double L = 0.0, V = 0.0;
    for (int k = t; k < GRID; k += BLOCK) { L += wsL[k]; V += wsV[k]; }
#pragma unroll
    for (int off = 32; off > 0; off >>= 1) {
        L += __shfl_down(L, off);
        V += __shfl_down(V, off);
    }
    if (lane == 0) { rl[wave] = L; rv[wave] = V; }
    __syncthreads();
    if (t == 0) {
        double Ls = rl[0] + rl[1] + rl[2] + rl[3];
        double Vs = rv[0] + rv[1] + rv[2] + rv[3];
        out[0] = (float)(Ls / ((double)N_ROWS * 151.0)
                       + 0.1 * (Vs / ((double)N_ROWS * 141.0)));
    }
}

extern "C" void kernel_launch(void* const* d_in, const int* in_sizes, int n_in,
                              void* d_out, int out_size, void* d_ws, size_t ws_size,
                              hipStream_t stream) {
    const float* preds   = (const float*)d_in[0];
    const float* targets = (const float*)d_in[1];
    float* wsL = (float*)d_ws;
    float* wsV = wsL + GRID;
    float* out = (float*)d_out;

    reg_loss_main<<<GRID, BLOCK, 0, stream>>>(preds, targets, wsL, wsV);
    reg_loss_finalize<<<1, BLOCK, 0, stream>>>(wsL, wsV, out);
}